// Round 22
// baseline (505.204 us; speedup 1.0000x reference)
//
#include <hip/hip_runtime.h>

typedef unsigned short u16;
typedef __attribute__((ext_vector_type(8))) short s16x8;
typedef __attribute__((ext_vector_type(4))) short s16x4;
typedef __attribute__((ext_vector_type(4))) float f32x4;

#define DEVI __device__ __forceinline__

DEVI u16 f2b(float f) {
  union { float f; unsigned u; } v; v.f = f;
  unsigned r = v.u + 0x7FFFu + ((v.u >> 16) & 1u);
  return (u16)(r >> 16);
}
DEVI float b2f(u16 h) {
  union { unsigned u; float f; } v; v.u = ((unsigned)h) << 16;
  return v.f;
}

typedef const __attribute__((address_space(1))) void gas_void;
typedef __attribute__((address_space(3))) void las_void;
DEVI void gload16(const void* g, void* l) {
  __builtin_amdgcn_global_load_lds((gas_void*)g, (las_void*)l, 16, 0, 0);
}

// Merged prep: blocks [0,6144) transpose Wqkv f32[4096][6144] -> bf16 Wt[N][K];
// blocks [6144,14336) convert x f32 -> bf16.
__global__ void prep_kernel(const float* __restrict__ x, const float* __restrict__ W,
                            u16* __restrict__ xb, u16* __restrict__ Wt) {
  __shared__ __attribute__((aligned(16))) u16 tile[64][68];
  const int t = threadIdx.x;
  const int bid = blockIdx.x;
  if (bid < 6144) {
    const int n0 = (bid % 96) * 64, k0 = (bid / 96) * 64;
    const int N = 6144, K = 4096;
#pragma unroll
    for (int i = 0; i < 4; ++i) {
      int c = i * 256 + t;
      int r = c >> 4, q = c & 15;
      float4 v = *(const float4*)(W + (size_t)(k0 + r) * N + n0 + q * 4);
      s16x4 o = {(short)f2b(v.x), (short)f2b(v.y), (short)f2b(v.z), (short)f2b(v.w)};
      *(s16x4*)&tile[r][q * 4] = o;
    }
    __syncthreads();
#pragma unroll
    for (int i = 0; i < 2; ++i) {
      int c = i * 256 + t;
      int n_ = c >> 3, ck = (c & 7) * 8;
      s16x8 o;
#pragma unroll
      for (int j = 0; j < 8; ++j) o[j] = (short)tile[ck + j][n_];
      *(s16x8*)(Wt + (size_t)(n0 + n_) * K + k0 + ck) = o;
    }
  } else {
    int i = (bid - 6144) * 256 + t;
    const float* p = x + (size_t)i * 8;
    float4 u = *(const float4*)p;
    float4 v = *(const float4*)(p + 4);
    s16x8 o = {(short)f2b(u.x), (short)f2b(u.y), (short)f2b(u.z), (short)f2b(u.w),
               (short)f2b(v.x), (short)f2b(v.y), (short)f2b(v.z), (short)f2b(v.w)};
    *(s16x8*)(xb + (size_t)i * 8) = o;
  }
}

// W [K][N] f32 -> Wt [N][K] bf16 (64x64 tiles) — used for Wout.
__global__ void trans_bf16(const float* __restrict__ W, u16* __restrict__ Wt, int K, int N) {
  __shared__ __attribute__((aligned(16))) u16 tile[64][68];
  const int t = threadIdx.x;
  const int n0 = blockIdx.x * 64, k0 = blockIdx.y * 64;
#pragma unroll
  for (int i = 0; i < 4; ++i) {
    int c = i * 256 + t;
    int r = c >> 4, q = c & 15;
    float4 v = *(const float4*)(W + (size_t)(k0 + r) * N + n0 + q * 4);
    s16x4 o = {(short)f2b(v.x), (short)f2b(v.y), (short)f2b(v.z), (short)f2b(v.w)};
    *(s16x4*)&tile[r][q * 4] = o;
  }
  __syncthreads();
#pragma unroll
  for (int i = 0; i < 2; ++i) {
    int c = i * 256 + t;
    int n_ = c >> 3, ck = (c & 7) * 8;
    s16x8 o;
#pragma unroll
    for (int j = 0; j < 8; ++j) o[j] = (short)tile[ck + j][n_];
    *(s16x8*)(Wt + (size_t)(n0 + n_) * K + k0 + ck) = o;
  }
}

// ---------------------------------------------------------------------------
// 128x256 bf16 GEMM (GEMM1): round-21 schedule (191 us, MfmaUtil 48%), XCD
// map refined to 2x4 grid: 2 row-halves x 4 col-bands of 6 cols. A L2-miss
// volume 268->134 MB (4 readers/row vs 8), B 50->100 MB; total 318->234 MB.
// Bijective: r2=xcd>>2, c4=xcd&3, j in [0,96): col=c4*6+j%6, row=r2*16+j/6.
// ---------------------------------------------------------------------------
__global__ __launch_bounds__(512, 2) void gemm128_g1(const u16* __restrict__ A,
                                                     const u16* __restrict__ Bt,
                                                     u16* __restrict__ C, int M, int N, int K) {
  __shared__ __attribute__((aligned(16))) u16 As[2][128 * 64];
  __shared__ __attribute__((aligned(16))) u16 Bs[2][256 * 64];
  const int t = threadIdx.x;
  const int xcd = blockIdx.x & 7, j = blockIdx.x >> 3;   // j in [0,96)
  const int row0 = (((xcd >> 2) << 4) + j / 6) << 7;     // 32 rows = 2 x 16
  const int col0 = (((xcd & 3) * 6) + (j % 6)) << 8;     // 24 cols = 4 x 6
  const int w = t >> 6, lane = t & 63, lc = lane & 15, lg = lane >> 4;
  const int wm = (w >> 2) * 64;
  const int wn4 = (w & 3);
  const int sw7 = lc & 7;

  const f32x4 FZ = {0.f, 0.f, 0.f, 0.f};
  f32x4 acc[4][4];
#pragma unroll
  for (int i = 0; i < 4; ++i)
#pragma unroll
    for (int j2 = 0; j2 < 4; ++j2) acc[i][j2] = FZ;

  const int ra = t >> 3;
  const int sa = (t & 7) ^ (ra & 7);
  const int bg0 = ((ra >> 5) << 6) | (ra & 31);

#define G1_STG_A(kt, sl)                                                          \
  {                                                                               \
    const u16* ap = A + (size_t)(row0 + ra) * K + ((kt) << 6) + (sa << 3);        \
    gload16(ap, (u16*)As[sl] + t * 8);                                            \
    gload16(ap + (size_t)64 * K, (u16*)As[sl] + (512 + t) * 8);                   \
  }
#define G1_STG_B(kt, H, sl)                                                       \
  {                                                                               \
    const u16* bp = Bt + (size_t)(col0 + bg0 + ((H) << 5)) * K + ((kt) << 6) + (sa << 3); \
    gload16(bp, (u16*)Bs[sl] + (H)*8192 + t * 8);                                 \
    gload16(bp + (size_t)128 * K, (u16*)Bs[sl] + (H)*8192 + (512 + t) * 8);       \
  }
#define G1_LOAD_A(buf)                                                            \
  _Pragma("unroll") for (int mf = 0; mf < 4; ++mf)                                \
  _Pragma("unroll") for (int ks = 0; ks < 2; ++ks)                                \
    af[mf][ks] = *(const s16x8*)(As[buf] + (wm + mf * 16 + lc) * 64 +             \
                                 (((ks * 4 + lg) ^ sw7) << 3));
#define G1_LOAD_B(NH, buf)                                                        \
  _Pragma("unroll") for (int nfl = 0; nfl < 2; ++nfl)                             \
  _Pragma("unroll") for (int ks = 0; ks < 2; ++ks)                                \
    bfv[nfl][ks] = *(const s16x8*)(Bs[buf] + ((NH)*128 + wn4 * 32 + nfl * 16 + lc) * 64 + \
                                   (((ks * 4 + lg) ^ sw7) << 3));
#define G1_MFMA(NH)                                                               \
  _Pragma("unroll") for (int ks = 0; ks < 2; ++ks)                                \
  _Pragma("unroll") for (int mf = 0; mf < 4; ++mf)                                \
  _Pragma("unroll") for (int nfl = 0; nfl < 2; ++nfl)                             \
    acc[mf][(NH)*2 + nfl] = __builtin_amdgcn_mfma_f32_16x16x32_bf16(              \
        af[mf][ks], bfv[nfl][ks], acc[mf][(NH)*2 + nfl], 0, 0, 0);
#define BAR __builtin_amdgcn_s_barrier()

  s16x8 af[4][2], bfv[2][2];
  const int NT = K >> 6, TM = NT - 1;

  G1_STG_A(0, 0) G1_STG_B(0, 0, 0) G1_STG_B(0, 1, 0)
  asm volatile("s_waitcnt vmcnt(2)" ::: "memory");
  BAR;

  for (int kt = 0; kt < NT; ++kt) {
    const int buf = kt & 1, nb = buf ^ 1;
    const int tp1 = (kt + 1) & TM;
    G1_LOAD_A(buf)
    G1_LOAD_B(0, buf)
    G1_STG_A(tp1, nb)
    G1_STG_B(tp1, 0, nb)
    BAR; G1_MFMA(0)
    asm volatile("s_waitcnt vmcnt(4)" ::: "memory");
    BAR;
    G1_LOAD_B(1, buf)
    G1_STG_B(tp1, 1, nb)
    BAR; G1_MFMA(1)
    asm volatile("s_waitcnt vmcnt(2)" ::: "memory");
    BAR;
  }
  asm volatile("s_waitcnt vmcnt(0)" ::: "memory");
#undef G1_STG_A
#undef G1_STG_B
#undef G1_LOAD_A
#undef G1_LOAD_B
#undef G1_MFMA
#undef BAR

#pragma unroll
  for (int mf = 0; mf < 4; ++mf)
#pragma unroll
    for (int nf = 0; nf < 4; ++nf)
#pragma unroll
      for (int r = 0; r < 4; ++r) {
        const int rg = row0 + wm + mf * 16 + lg * 4 + r;
        const int cg = col0 + wn4 * 64 + (nf >> 1) * 32 + (nf & 1) * 16 + lc;
        C[(size_t)rg * N + cg] = f2b(acc[mf][nf][r]);
      }
}

// ---------------------------------------------------------------------------
// 256x256 bf16 GEMM (GEMM2): round-21 version (quadrant XCD map, no setprio).
// ---------------------------------------------------------------------------
__global__ __launch_bounds__(512, 2) void gemm256_g2(const u16* __restrict__ A,
                                                     const u16* __restrict__ Bt,
                                                     float* __restrict__ C, int M, int N, int K) {
  __shared__ __attribute__((aligned(16))) u16 As[2][2][128 * 64];  // [buf][half]
  __shared__ __attribute__((aligned(16))) u16 Bs[2][2][128 * 64];
  const int t = threadIdx.x;
  const int xcd = blockIdx.x & 7, j = blockIdx.x >> 3;   // j in [0,32)
  const int row0 = (((xcd >> 2) * 8) + (j >> 2)) << 8;   // 16 rows = 2 XCD x 8
  const int col0 = (((xcd & 3) * 4) + (j & 3)) << 8;     // 16 cols = 4 XCD x 4
  const int w = t >> 6, lane = t & 63, lc = lane & 15, lg = lane >> 4;
  const int wqm = (w >> 2) * 64;
  const int wqn = (w & 3) * 32;
  const int sw7 = lc & 7;

  const f32x4 FZ = {0.f, 0.f, 0.f, 0.f};
  f32x4 acc[4][4][2];
#pragma unroll
  for (int q = 0; q < 4; ++q)
#pragma unroll
    for (int i = 0; i < 4; ++i)
#pragma unroll
      for (int j2 = 0; j2 < 2; ++j2) acc[q][i][j2] = FZ;

  const int s_r0 = t >> 3, s_r1 = (512 + t) >> 3;
  const int s_s = t & 7;

#define STG_A(kt, H, sl)                                                                   \
  {                                                                                        \
    gload16(A + (size_t)(row0 + (H)*128 + s_r0) * K + ((kt) << 6) + ((s_s ^ (s_r0 & 7)) << 3), \
            (u16*)As[sl][H] + t * 8);                                                      \
    gload16(A + (size_t)(row0 + (H)*128 + s_r1) * K + ((kt) << 6) + ((s_s ^ (s_r1 & 7)) << 3), \
            (u16*)As[sl][H] + (512 + t) * 8);                                              \
  }
#define STG_B(kt, H, sl)                                                                   \
  {                                                                                        \
    gload16(Bt + (size_t)(col0 + (H)*128 + s_r0) * K + ((kt) << 6) + ((s_s ^ (s_r0 & 7)) << 3), \
            (u16*)Bs[sl][H] + t * 8);                                                      \
    gload16(Bt + (size_t)(col0 + (H)*128 + s_r1) * K + ((kt) << 6) + ((s_s ^ (s_r1 & 7)) << 3), \
            (u16*)Bs[sl][H] + (512 + t) * 8);                                              \
  }
#define LOAD_A(MH, buf)                                                           \
  _Pragma("unroll") for (int mf = 0; mf < 4; ++mf)                                \
  _Pragma("unroll") for (int ks = 0; ks < 2; ++ks)                                \
    af[mf][ks] = *(const s16x8*)(As[buf][MH] + (wqm + mf * 16 + lc) * 64 +        \
                                 (((ks * 4 + lg) ^ sw7) << 3));
#define LOAD_B(NH, buf, DST)                                                      \
  _Pragma("unroll") for (int nf = 0; nf < 2; ++nf)                                \
  _Pragma("unroll") for (int ks = 0; ks < 2; ++ks)                                \
    DST[nf][ks] = *(const s16x8*)(Bs[buf][NH] + (wqn + nf * 16 + lc) * 64 +       \
                                  (((ks * 4 + lg) ^ sw7) << 3));
#define MFMA_Q(q, BV)                                                             \
  _Pragma("unroll") for (int ks = 0; ks < 2; ++ks)                                \
  _Pragma("unroll") for (int mf = 0; mf < 4; ++mf)                                \
  _Pragma("unroll") for (int nf = 0; nf < 2; ++nf)                                \
    acc[q][mf][nf] = __builtin_amdgcn_mfma_f32_16x16x32_bf16(                     \
        af[mf][ks], BV[nf][ks], acc[q][mf][nf], 0, 0, 0);
#define BAR __builtin_amdgcn_s_barrier()
#define WAIT6 asm volatile("s_waitcnt vmcnt(6)" ::: "memory")

  s16x8 af[4][2], bfv0[2][2], bfv1[2][2];
  const int NT = K >> 6, TM = NT - 1;

  STG_A(0, 0, 0) STG_B(0, 0, 0) STG_B(0, 1, 0) STG_A(0, 1, 0)
  STG_A(1, 0, 1) STG_B(1, 0, 1) STG_B(1, 1, 1)
  WAIT6;
  BAR;

  for (int kt = 0; kt < NT; ++kt) {
    const int buf = kt & 1, nb = buf ^ 1;
    const int tp1 = (kt + 1) & TM, tp2 = (kt + 2) & TM;
    LOAD_A(0, buf) LOAD_B(0, buf, bfv0)
    STG_A(tp1, 1, nb)
    BAR; MFMA_Q(0, bfv0) BAR;
    LOAD_B(1, buf, bfv1)
    STG_A(tp2, 0, buf)
    BAR; MFMA_Q(1, bfv1) BAR;
    LOAD_A(1, buf)
    STG_B(tp2, 0, buf)
    BAR; MFMA_Q(2, bfv1) BAR;
    STG_B(tp2, 1, buf)
    BAR; MFMA_Q(3, bfv0)
    WAIT6;
    BAR;
  }
  asm volatile("s_waitcnt vmcnt(0)" ::: "memory");
  BAR;
#undef STG_A
#undef STG_B
#undef LOAD_A
#undef LOAD_B
#undef MFMA_Q
#undef BAR
#undef WAIT6

  const int qmh[4] = {0, 0, 1, 1}, qnh[4] = {0, 1, 1, 0};
#pragma unroll
  for (int q = 0; q < 4; ++q)
#pragma unroll
    for (int mf = 0; mf < 4; ++mf)
#pragma unroll
      for (int nf = 0; nf < 2; ++nf)
#pragma unroll
        for (int r = 0; r < 4; ++r) {
          const int rg = row0 + qmh[q] * 128 + wqm + mf * 16 + lg * 4 + r;
          const int cg = col0 + qnh[q] * 128 + wqn + nf * 16 + lc;
          C[(size_t)rg * N + cg] = acc[q][mf][nf][r];
        }
}

// Merged rope + vtrans (disjoint qkv column ranges).
__global__ void rv_kernel(u16* __restrict__ qkv, const float* __restrict__ cosb,
                          const float* __restrict__ sinb, u16* __restrict__ v_t) {
  __shared__ __attribute__((aligned(16))) u16 tile[64][72];
  const int t = threadIdx.x;
  const int bid = blockIdx.x;
  if (bid < 5120) {
    const int idx = bid * 256 + t;
    const int bs = idx / 320;
    const int p = idx - bs * 320;
    const int s = bs & 2047;
    u16* row = qkv + (size_t)bs * 6144;
    const float* cr = cosb + s * 128;
    const float* sr = sinb + s * 128;
    const float SC2 = 0.08838834764831845f * 1.44269504088896340736f;
    const int head = p >> 3, dc = (p & 7) * 8;
    const int ci = head * 128 + dc;
    const float m = (head < 32) ? SC2 : 1.0f;
    s16x8 a = *(const s16x8*)&row[ci];
    s16x8 bb = *(const s16x8*)&row[ci + 64];
    float4 c0 = *(const float4*)(cr + dc), c1 = *(const float4*)(cr + dc + 4);
    float4 s0 = *(const float4*)(sr + dc), s1 = *(const float4*)(sr + dc + 4);
    float cv[8] = {c0.x, c0.y, c0.z, c0.w, c1.x, c1.y, c1.z, c1.w};
    float sv[8] = {s0.x, s0.y, s0.z, s0.w, s1.x, s1.y, s1.z, s1.w};
    s16x8 o1, o2;
#pragma unroll
    for (int j = 0; j < 8; ++j) {
      float x1 = b2f((u16)a[j]), x2 = b2f((u16)bb[j]);
      o1[j] = (short)f2b((x1 * cv[j] - x2 * sv[j]) * m);
      o2[j] = (short)f2b((x2 * cv[j] + x1 * sv[j]) * m);
    }
    *(s16x8*)&row[ci] = o1;
    *(s16x8*)&row[ci + 64] = o2;
  } else {
    const int vb = bid - 5120;
    const int s0 = (vb & 31) * 64;
    const int d0 = ((vb >> 5) & 1) * 64;
    const int bk = vb >> 6;
    const int b = bk >> 3, kvh = bk & 7;
    const int slot = t & 7, r0 = t >> 3;
#pragma unroll
    for (int i = 0; i < 2; ++i) {
      int s_ = r0 + 32 * i;
      *(s16x8*)&tile[s_][slot * 8] =
          *(const s16x8*)(qkv + (size_t)(b * 2048 + s0 + s_) * 6144 + 5120 + kvh * 128 + d0 + slot * 8);
    }
    __syncthreads();
#pragma unroll
    for (int i = 0; i < 2; ++i) {
      int d_ = r0 + 32 * i;
      s16x8 v;
#pragma unroll
      for (int j = 0; j < 8; ++j) v[j] = (short)tile[slot * 8 + j][d_];
      *(s16x8*)(v_t + ((size_t)bk * 128 + d0 + d_) * 2048 + s0 + slot * 8) = v;
    }
  }
}

// Flash causal attention (round-15 champion).
__global__ void __launch_bounds__(256, 2) attn_kernel(const u16* __restrict__ qkv,
                                                      const u16* __restrict__ v_t,
                                                      u16* __restrict__ attn) {
  __shared__ __attribute__((aligned(16))) u16 Ks[64][136];
  __shared__ __attribute__((aligned(16))) u16 Vs[128][72];
  __shared__ __attribute__((aligned(16))) u16 Ps[4][32][72];
  const int t = threadIdx.x;
  const int f = blockIdx.x;
  const int xcd = f & 7, ix = f >> 3;
  const int g = (xcd << 1) | (ix >> 6);
  const int r_ = ix & 63;
  const int b = g >> 3, kvh = g & 7;
  const int qt = 15 - (r_ >> 2);
  const int h = kvh * 4 + (r_ & 3);
  const int q0 = qt * 128;
  const int w = t >> 6, lane = t & 63, lc = lane & 15, lg = lane >> 4;
  const int qw = q0 + w * 32;

  const u16* qbase = qkv + (size_t)(b * 2048) * 6144 + h * 128;
  const u16* kbase = qkv + (size_t)(b * 2048) * 6144 + 4096 + kvh * 128;
  const u16* vbase = v_t + (size_t)(b * 8 + kvh) * 128 * 2048;

  s16x8 qf[2][4];
#pragma unroll
  for (int mf = 0; mf < 2; ++mf)
#pragma unroll
    for (int ks = 0; ks < 4; ++ks)
      qf[mf][ks] = *(const s16x8*)(qbase + (size_t)(qw + mf * 16 + lc) * 6144 + ks * 32 + lg * 8);

  const f32x4 FZ = {0.f, 0.f, 0.f, 0.f};
  const short ONE = (short)0x3F80;
  const s16x8 ONES = {ONE, ONE, ONE, ONE, ONE, ONE, ONE, ONE};
  f32x4 o_acc[2][8];
  f32x4 l9[2];
  float m_run[2][4];
#pragma unroll
  for (int mf = 0; mf < 2; ++mf) {
#pragma unroll
    for (int nf = 0; nf < 8; ++nf) o_acc[mf][nf] = FZ;
    l9[mf] = FZ;
#pragma unroll
    for (int r = 0; r < 4; ++r) m_run[mf][r] = -3e38f;
  }

  const int ntiles = q0 / 64 + 2;
  s16x8 kr[4], vr[4];
#pragma unroll
  for (int i = 0; i < 4; ++i) {
    int c = i * 256 + t;
    kr[i] = *(const s16x8*)(kbase + (size_t)(c >> 4) * 6144 + (c & 15) * 8);
    vr[i] = *(const s16x8*)(vbase + (size_t)(c >> 3) * 2048 + (c & 7) * 8);
  }

  for (int kt = 0; kt < ntiles; ++kt) {
    const int k0 = kt * 64;
    __syncthreads();
#pragma unroll
    for (int i = 0; i < 4; ++i) {
      int c = i * 256 + t;
      *(s16x8*)&Ks[c >> 4][(c & 15) * 8] = kr[i];
      *(s16x8*)&Vs[c >> 3][(c & 7) * 8] = vr[i];
    }
    __syncthreads();
    if (kt + 1 < ntiles) {
      int k1 = k0 + 64;
#pragma unroll
      for (int i = 0; i < 4; ++i) {
        int c = i * 256 + t;
        kr[i] = *(const s16x8*)(kbase + (size_t)(k1 + (c >> 4)) * 6144 + (c & 15) * 8);
        vr[i] = *(const s16x8*)(vbase + (size_t)(c >> 3) * 2048 + k1 + (c & 7) * 8);
      }
    }
    if (k0 > qw + 31) continue;

    f32x4 sacc[2][4];
#pragma unroll
    for (int mf = 0; mf < 2; ++mf)
#pragma unroll
      for (int nf = 0; nf < 4; ++nf) sacc[mf][nf] = FZ;
#pragma unroll
    for (int ks = 0; ks < 4; ++ks) {
      s16x8 kf[4];
#pragma unroll
      for (int nf = 0; nf < 4; ++nf)
        kf[nf] = *(const s16x8*)&Ks[nf * 16 + lc][ks * 32 + lg * 8];
#pragma unroll
      for (int mf = 0; mf < 2; ++mf)
#pragma unroll
        for (int nf = 0; nf < 4; ++nf)
          sacc[mf][nf] = __builtin_amdgcn_mfma_f32_16x16x32_bf16(qf[mf][ks], kf[nf], sacc[mf][nf], 0, 0, 0);
    }

#pragma unroll
    for (int mf = 0; mf < 2; ++mf) {
      float pm[4] = {-3e38f, -3e38f, -3e38f, -3e38f};
      const bool dm = (k0 + 63 > qw + mf * 16);
      if (dm) {
#pragma unroll
        for (int nf = 0; nf < 4; ++nf) {
          int kv = k0 + nf * 16 + lc;
#pragma unroll
          for (int r = 0; r < 4; ++r) {
            int qg = qw + mf * 16 + lg * 4 + r;
            float sv = (kv <= qg) ? sacc[mf][nf][r] : -3e38f;
            sacc[mf][nf][r] = sv;
            pm[r] = fmaxf(pm[r], sv);
          }
        }
      } else {
#pragma unroll
        for (int nf = 0; nf < 4; ++nf)
#pragma unroll
          for (int r = 0; r < 4; ++r) pm[r] = fmaxf(pm[r], sacc[mf][nf][r]);
      }
#pragma unroll
      for (int r = 0; r < 4; ++r) {
        pm[r] = fmaxf(pm[r], __shfl_xor(pm[r], 1));
        pm[r] = fmaxf(pm[r], __shfl_xor(pm[r], 2));
        pm[r] = fmaxf(pm[r], __shfl_xor(pm[r], 4));
        pm[r] = fmaxf(pm[r], __shfl_xor(pm[r], 8));
      }
      bool need = false;
#pragma unroll
      for (int r = 0; r < 4; ++r) need |= (pm[r] > m_run[mf][r] + 8.0f);
      if (__any(need)) {
#pragma unroll
        for (int r = 0; r < 4; ++r) {
          float mnew = fmaxf(m_run[mf][r], pm[r]);
          float fsc = exp2f(m_run[mf][r] - mnew);
          m_run[mf][r] = mnew;
          l9[mf][r] *= fsc;
#pragma unroll
          for (int nf = 0; nf < 8; ++nf) o_acc[mf][nf][r] *= fsc;
        }
      }
#pragma unroll
      for (int nf = 0; nf < 4; ++nf)
#pragma unroll
        for (int r = 0; r < 4; ++r) {
          float p = exp2f(sacc[mf][nf][r] - m_run[mf][r]);
          Ps[w][mf * 16 + lg * 4 + r][nf * 16 + lc] = f2b(p);
        }
    }
#pragma unroll
    for (int ks = 0; ks < 2; ++ks) {
      s16x8 pf[2];
#pragma unroll
      for (int mf = 0; mf < 2; ++mf)
        pf[mf] = *(const s16x8*)&Ps[w][mf * 16 + lc][ks * 32 + lg * 8];
#pragma unroll
      for (int mf = 0; mf < 2; ++mf)
        l9[mf] = __builtin_amdgcn_mfma_f32_16x16x32_bf16(pf[mf], ONES, l9[mf], 0, 0, 0);
#pragma unroll
      for (int nf = 0; nf < 8; ++nf) {
        s16x8 vf = *(const s16x8*)&Vs[nf * 16 + lc][ks * 32 + lg * 8];
#pragma unroll
        for (int mf = 0; mf < 2; ++mf)
          o_acc[mf][nf] = __builtin_amdgcn_mfma_f32_16x16x32_bf16(pf[mf], vf, o_acc[mf][nf], 0, 0, 0);
      }
    }
  }

#pragma unroll
  for (int mf = 0; mf < 2; ++mf)
#pragma unroll
    for (int r = 0; r < 4; ++r) {
      float inv = 1.0f / l9[mf][r];
      int qg = qw + mf * 16 + lg * 4 + r;
#pragma unroll
      for (int nf = 0; nf < 8; ++nf)
        attn[(size_t)(b * 2048 + qg) * 4096 + h * 128 + nf * 16 + lc] =
            f2b(o_acc[mf][nf][r] * inv);
    }
}

extern "C" void kernel_launch(void* const* d_in, const int* in_sizes, int n_in,
                              void* d_out, int out_size, void* d_ws, size_t ws_size,
                              hipStream_t stream) {
  (void)in_sizes; (void)n_in; (void)out_size; (void)ws_size;
  const float* x = (const float*)d_in[0];
  const float* cosb = (const float*)d_in[1];
  const float* sinb = (const float*)d_in[2];
  const float* Wqkv = (const float*)d_in[3];
  const float* Wout = (const float*)d_in[4];
  float* out = (float*)d_out;
  char* ws = (char*)d_ws;

  u16* buf0 = (u16*)ws;
  u16* buf1 = (u16*)(ws + 50331648);
  u16* regc = (u16*)(ws + 100663296);

  prep_kernel<<<14336, 256, 0, stream>>>(x, Wqkv, regc, buf0);                  // xb + Wqkv_t
  gemm128_g1<<<768, 512, 0, stream>>>(regc, buf0, buf1, 4096, 6144, 4096);      // qkv (2x4 XCD map)
  rv_kernel<<<6144, 256, 0, stream>>>(buf1, cosb, sinb, regc);                  // rope + v_t (merged)
  attn_kernel<<<1024, 256, 0, stream>>>(buf1, regc, buf0);                      // attn_out
  trans_bf16<<<dim3(64, 64), 256, 0, stream>>>(Wout, regc, 4096, 4096);         // Wout_t
  gemm256_g2<<<256, 512, 0, stream>>>(buf0, regc, out, 4096, 4096, 4096);       // out (quadrant XCD map)
}

// Round 23
// 502.622 us; speedup vs baseline: 1.0051x; 1.0051x over previous
//
#include <hip/hip_runtime.h>

typedef unsigned short u16;
typedef __attribute__((ext_vector_type(8))) short s16x8;
typedef __attribute__((ext_vector_type(4))) short s16x4;
typedef __attribute__((ext_vector_type(4))) float f32x4;

#define DEVI __device__ __forceinline__

DEVI u16 f2b(float f) {
  union { float f; unsigned u; } v; v.f = f;
  unsigned r = v.u + 0x7FFFu + ((v.u >> 16) & 1u);
  return (u16)(r >> 16);
}
DEVI float b2f(u16 h) {
  union { unsigned u; float f; } v; v.u = ((unsigned)h) << 16;
  return v.f;
}

typedef const __attribute__((address_space(1))) void gas_void;
typedef __attribute__((address_space(3))) void las_void;
DEVI void gload16(const void* g, void* l) {
  __builtin_amdgcn_global_load_lds((gas_void*)g, (las_void*)l, 16, 0, 0);
}

// Merged prep: blocks [0,6144) transpose Wqkv f32[4096][6144] -> bf16 Wt[N][K];
// blocks [6144,14336) convert x f32 -> bf16.
__global__ void prep_kernel(const float* __restrict__ x, const float* __restrict__ W,
                            u16* __restrict__ xb, u16* __restrict__ Wt) {
  __shared__ __attribute__((aligned(16))) u16 tile[64][68];
  const int t = threadIdx.x;
  const int bid = blockIdx.x;
  if (bid < 6144) {
    const int n0 = (bid % 96) * 64, k0 = (bid / 96) * 64;
    const int N = 6144, K = 4096;
#pragma unroll
    for (int i = 0; i < 4; ++i) {
      int c = i * 256 + t;
      int r = c >> 4, q = c & 15;
      float4 v = *(const float4*)(W + (size_t)(k0 + r) * N + n0 + q * 4);
      s16x4 o = {(short)f2b(v.x), (short)f2b(v.y), (short)f2b(v.z), (short)f2b(v.w)};
      *(s16x4*)&tile[r][q * 4] = o;
    }
    __syncthreads();
#pragma unroll
    for (int i = 0; i < 2; ++i) {
      int c = i * 256 + t;
      int n_ = c >> 3, ck = (c & 7) * 8;
      s16x8 o;
#pragma unroll
      for (int j = 0; j < 8; ++j) o[j] = (short)tile[ck + j][n_];
      *(s16x8*)(Wt + (size_t)(n0 + n_) * K + k0 + ck) = o;
    }
  } else {
    int i = (bid - 6144) * 256 + t;
    const float* p = x + (size_t)i * 8;
    float4 u = *(const float4*)p;
    float4 v = *(const float4*)(p + 4);
    s16x8 o = {(short)f2b(u.x), (short)f2b(u.y), (short)f2b(u.z), (short)f2b(u.w),
               (short)f2b(v.x), (short)f2b(v.y), (short)f2b(v.z), (short)f2b(v.w)};
    *(s16x8*)(xb + (size_t)i * 8) = o;
  }
}

// W [K][N] f32 -> Wt [N][K] bf16 (64x64 tiles) — used for Wout.
__global__ void trans_bf16(const float* __restrict__ W, u16* __restrict__ Wt, int K, int N) {
  __shared__ __attribute__((aligned(16))) u16 tile[64][68];
  const int t = threadIdx.x;
  const int n0 = blockIdx.x * 64, k0 = blockIdx.y * 64;
#pragma unroll
  for (int i = 0; i < 4; ++i) {
    int c = i * 256 + t;
    int r = c >> 4, q = c & 15;
    float4 v = *(const float4*)(W + (size_t)(k0 + r) * N + n0 + q * 4);
    s16x4 o = {(short)f2b(v.x), (short)f2b(v.y), (short)f2b(v.z), (short)f2b(v.w)};
    *(s16x4*)&tile[r][q * 4] = o;
  }
  __syncthreads();
#pragma unroll
  for (int i = 0; i < 2; ++i) {
    int c = i * 256 + t;
    int n_ = c >> 3, ck = (c & 7) * 8;
    s16x8 o;
#pragma unroll
    for (int j = 0; j < 8; ++j) o[j] = (short)tile[ck + j][n_];
    *(s16x8*)(Wt + (size_t)(n0 + n_) * K + k0 + ck) = o;
  }
}

// ---------------------------------------------------------------------------
// 128x256 bf16 GEMM (GEMM1): round-21 champion config (190.6 us, MfmaUtil
// 48-49%, FETCH 215MB). Col-band XCD map: xcd=bid&7, j=bid>>3, col=xcd*3+j%3,
// row=j/3. No setprio. r22's 2x4 map A/B'd null -> keep the simpler map.
// ---------------------------------------------------------------------------
__global__ __launch_bounds__(512, 2) void gemm128_g1(const u16* __restrict__ A,
                                                     const u16* __restrict__ Bt,
                                                     u16* __restrict__ C, int M, int N, int K) {
  __shared__ __attribute__((aligned(16))) u16 As[2][128 * 64];
  __shared__ __attribute__((aligned(16))) u16 Bs[2][256 * 64];
  const int t = threadIdx.x;
  const int xcd = blockIdx.x & 7, j = blockIdx.x >> 3;
  const int row0 = (j / 3) << 7;                 // 32 rows
  const int col0 = (xcd * 3 + (j % 3)) << 8;     // 24 cols = 8 XCD x 3
  const int w = t >> 6, lane = t & 63, lc = lane & 15, lg = lane >> 4;
  const int wm = (w >> 2) * 64;
  const int wn4 = (w & 3);
  const int sw7 = lc & 7;

  const f32x4 FZ = {0.f, 0.f, 0.f, 0.f};
  f32x4 acc[4][4];
#pragma unroll
  for (int i = 0; i < 4; ++i)
#pragma unroll
    for (int j2 = 0; j2 < 4; ++j2) acc[i][j2] = FZ;

  const int ra = t >> 3;
  const int sa = (t & 7) ^ (ra & 7);
  const int bg0 = ((ra >> 5) << 6) | (ra & 31);

#define G1_STG_A(kt, sl)                                                          \
  {                                                                               \
    const u16* ap = A + (size_t)(row0 + ra) * K + ((kt) << 6) + (sa << 3);        \
    gload16(ap, (u16*)As[sl] + t * 8);                                            \
    gload16(ap + (size_t)64 * K, (u16*)As[sl] + (512 + t) * 8);                   \
  }
#define G1_STG_B(kt, H, sl)                                                       \
  {                                                                               \
    const u16* bp = Bt + (size_t)(col0 + bg0 + ((H) << 5)) * K + ((kt) << 6) + (sa << 3); \
    gload16(bp, (u16*)Bs[sl] + (H)*8192 + t * 8);                                 \
    gload16(bp + (size_t)128 * K, (u16*)Bs[sl] + (H)*8192 + (512 + t) * 8);       \
  }
#define G1_LOAD_A(buf)                                                            \
  _Pragma("unroll") for (int mf = 0; mf < 4; ++mf)                                \
  _Pragma("unroll") for (int ks = 0; ks < 2; ++ks)                                \
    af[mf][ks] = *(const s16x8*)(As[buf] + (wm + mf * 16 + lc) * 64 +             \
                                 (((ks * 4 + lg) ^ sw7) << 3));
#define G1_LOAD_B(NH, buf)                                                        \
  _Pragma("unroll") for (int nfl = 0; nfl < 2; ++nfl)                             \
  _Pragma("unroll") for (int ks = 0; ks < 2; ++ks)                                \
    bfv[nfl][ks] = *(const s16x8*)(Bs[buf] + ((NH)*128 + wn4 * 32 + nfl * 16 + lc) * 64 + \
                                   (((ks * 4 + lg) ^ sw7) << 3));
#define G1_MFMA(NH)                                                               \
  _Pragma("unroll") for (int ks = 0; ks < 2; ++ks)                                \
  _Pragma("unroll") for (int mf = 0; mf < 4; ++mf)                                \
  _Pragma("unroll") for (int nfl = 0; nfl < 2; ++nfl)                             \
    acc[mf][(NH)*2 + nfl] = __builtin_amdgcn_mfma_f32_16x16x32_bf16(              \
        af[mf][ks], bfv[nfl][ks], acc[mf][(NH)*2 + nfl], 0, 0, 0);
#define BAR __builtin_amdgcn_s_barrier()

  s16x8 af[4][2], bfv[2][2];
  const int NT = K >> 6, TM = NT - 1;

  G1_STG_A(0, 0) G1_STG_B(0, 0, 0) G1_STG_B(0, 1, 0)
  asm volatile("s_waitcnt vmcnt(2)" ::: "memory");
  BAR;

  for (int kt = 0; kt < NT; ++kt) {
    const int buf = kt & 1, nb = buf ^ 1;
    const int tp1 = (kt + 1) & TM;
    G1_LOAD_A(buf)
    G1_LOAD_B(0, buf)
    G1_STG_A(tp1, nb)
    G1_STG_B(tp1, 0, nb)
    BAR; G1_MFMA(0)
    asm volatile("s_waitcnt vmcnt(4)" ::: "memory");
    BAR;
    G1_LOAD_B(1, buf)
    G1_STG_B(tp1, 1, nb)
    BAR; G1_MFMA(1)
    asm volatile("s_waitcnt vmcnt(2)" ::: "memory");
    BAR;
  }
  asm volatile("s_waitcnt vmcnt(0)" ::: "memory");
#undef G1_STG_A
#undef G1_STG_B
#undef G1_LOAD_A
#undef G1_LOAD_B
#undef G1_MFMA
#undef BAR

#pragma unroll
  for (int mf = 0; mf < 4; ++mf)
#pragma unroll
    for (int nf = 0; nf < 4; ++nf)
#pragma unroll
      for (int r = 0; r < 4; ++r) {
        const int rg = row0 + wm + mf * 16 + lg * 4 + r;
        const int cg = col0 + wn4 * 64 + (nf >> 1) * 32 + (nf & 1) * 16 + lc;
        C[(size_t)rg * N + cg] = f2b(acc[mf][nf][r]);
      }
}

// ---------------------------------------------------------------------------
// 256x256 bf16 GEMM (GEMM2): quadrant XCD map, no setprio (round-21 config).
// ---------------------------------------------------------------------------
__global__ __launch_bounds__(512, 2) void gemm256_g2(const u16* __restrict__ A,
                                                     const u16* __restrict__ Bt,
                                                     float* __restrict__ C, int M, int N, int K) {
  __shared__ __attribute__((aligned(16))) u16 As[2][2][128 * 64];  // [buf][half]
  __shared__ __attribute__((aligned(16))) u16 Bs[2][2][128 * 64];
  const int t = threadIdx.x;
  const int xcd = blockIdx.x & 7, j = blockIdx.x >> 3;   // j in [0,32)
  const int row0 = (((xcd >> 2) * 8) + (j >> 2)) << 8;   // 16 rows = 2 XCD x 8
  const int col0 = (((xcd & 3) * 4) + (j & 3)) << 8;     // 16 cols = 4 XCD x 4
  const int w = t >> 6, lane = t & 63, lc = lane & 15, lg = lane >> 4;
  const int wqm = (w >> 2) * 64;
  const int wqn = (w & 3) * 32;
  const int sw7 = lc & 7;

  const f32x4 FZ = {0.f, 0.f, 0.f, 0.f};
  f32x4 acc[4][4][2];
#pragma unroll
  for (int q = 0; q < 4; ++q)
#pragma unroll
    for (int i = 0; i < 4; ++i)
#pragma unroll
      for (int j2 = 0; j2 < 2; ++j2) acc[q][i][j2] = FZ;

  const int s_r0 = t >> 3, s_r1 = (512 + t) >> 3;
  const int s_s = t & 7;

#define STG_A(kt, H, sl)                                                                   \
  {                                                                                        \
    gload16(A + (size_t)(row0 + (H)*128 + s_r0) * K + ((kt) << 6) + ((s_s ^ (s_r0 & 7)) << 3), \
            (u16*)As[sl][H] + t * 8);                                                      \
    gload16(A + (size_t)(row0 + (H)*128 + s_r1) * K + ((kt) << 6) + ((s_s ^ (s_r1 & 7)) << 3), \
            (u16*)As[sl][H] + (512 + t) * 8);                                              \
  }
#define STG_B(kt, H, sl)                                                                   \
  {                                                                                        \
    gload16(Bt + (size_t)(col0 + (H)*128 + s_r0) * K + ((kt) << 6) + ((s_s ^ (s_r0 & 7)) << 3), \
            (u16*)Bs[sl][H] + t * 8);                                                      \
    gload16(Bt + (size_t)(col0 + (H)*128 + s_r1) * K + ((kt) << 6) + ((s_s ^ (s_r1 & 7)) << 3), \
            (u16*)Bs[sl][H] + (512 + t) * 8);                                              \
  }
#define LOAD_A(MH, buf)                                                           \
  _Pragma("unroll") for (int mf = 0; mf < 4; ++mf)                                \
  _Pragma("unroll") for (int ks = 0; ks < 2; ++ks)                                \
    af[mf][ks] = *(const s16x8*)(As[buf][MH] + (wqm + mf * 16 + lc) * 64 +        \
                                 (((ks * 4 + lg) ^ sw7) << 3));
#define LOAD_B(NH, buf, DST)                                                      \
  _Pragma("unroll") for (int nf = 0; nf < 2; ++nf)                                \
  _Pragma("unroll") for (int ks = 0; ks < 2; ++ks)                                \
    DST[nf][ks] = *(const s16x8*)(Bs[buf][NH] + (wqn + nf * 16 + lc) * 64 +       \
                                  (((ks * 4 + lg) ^ sw7) << 3));
#define MFMA_Q(q, BV)                                                             \
  _Pragma("unroll") for (int ks = 0; ks < 2; ++ks)                                \
  _Pragma("unroll") for (int mf = 0; mf < 4; ++mf)                                \
  _Pragma("unroll") for (int nf = 0; nf < 2; ++nf)                                \
    acc[q][mf][nf] = __builtin_amdgcn_mfma_f32_16x16x32_bf16(                     \
        af[mf][ks], BV[nf][ks], acc[q][mf][nf], 0, 0, 0);
#define BAR __builtin_amdgcn_s_barrier()
#define WAIT6 asm volatile("s_waitcnt vmcnt(6)" ::: "memory")

  s16x8 af[4][2], bfv0[2][2], bfv1[2][2];
  const int NT = K >> 6, TM = NT - 1;

  STG_A(0, 0, 0) STG_B(0, 0, 0) STG_B(0, 1, 0) STG_A(0, 1, 0)
  STG_A(1, 0, 1) STG_B(1, 0, 1) STG_B(1, 1, 1)
  WAIT6;
  BAR;

  for (int kt = 0; kt < NT; ++kt) {
    const int buf = kt & 1, nb = buf ^ 1;
    const int tp1 = (kt + 1) & TM, tp2 = (kt + 2) & TM;
    LOAD_A(0, buf) LOAD_B(0, buf, bfv0)
    STG_A(tp1, 1, nb)
    BAR; MFMA_Q(0, bfv0) BAR;
    LOAD_B(1, buf, bfv1)
    STG_A(tp2, 0, buf)
    BAR; MFMA_Q(1, bfv1) BAR;
    LOAD_A(1, buf)
    STG_B(tp2, 0, buf)
    BAR; MFMA_Q(2, bfv1) BAR;
    STG_B(tp2, 1, buf)
    BAR; MFMA_Q(3, bfv0)
    WAIT6;
    BAR;
  }
  asm volatile("s_waitcnt vmcnt(0)" ::: "memory");
  BAR;
#undef STG_A
#undef STG_B
#undef LOAD_A
#undef LOAD_B
#undef MFMA_Q
#undef BAR
#undef WAIT6

  const int qmh[4] = {0, 0, 1, 1}, qnh[4] = {0, 1, 1, 0};
#pragma unroll
  for (int q = 0; q < 4; ++q)
#pragma unroll
    for (int mf = 0; mf < 4; ++mf)
#pragma unroll
      for (int nf = 0; nf < 2; ++nf)
#pragma unroll
        for (int r = 0; r < 4; ++r) {
          const int rg = row0 + qmh[q] * 128 + wqm + mf * 16 + lg * 4 + r;
          const int cg = col0 + qnh[q] * 128 + wqn + nf * 16 + lc;
          C[(size_t)rg * N + cg] = acc[q][mf][nf][r];
        }
}

// Merged rope + vtrans (disjoint qkv column ranges).
__global__ void rv_kernel(u16* __restrict__ qkv, const float* __restrict__ cosb,
                          const float* __restrict__ sinb, u16* __restrict__ v_t) {
  __shared__ __attribute__((aligned(16))) u16 tile[64][72];
  const int t = threadIdx.x;
  const int bid = blockIdx.x;
  if (bid < 5120) {
    const int idx = bid * 256 + t;
    const int bs = idx / 320;
    const int p = idx - bs * 320;
    const int s = bs & 2047;
    u16* row = qkv + (size_t)bs * 6144;
    const float* cr = cosb + s * 128;
    const float* sr = sinb + s * 128;
    const float SC2 = 0.08838834764831845f * 1.44269504088896340736f;
    const int head = p >> 3, dc = (p & 7) * 8;
    const int ci = head * 128 + dc;
    const float m = (head < 32) ? SC2 : 1.0f;
    s16x8 a = *(const s16x8*)&row[ci];
    s16x8 bb = *(const s16x8*)&row[ci + 64];
    float4 c0 = *(const float4*)(cr + dc), c1 = *(const float4*)(cr + dc + 4);
    float4 s0 = *(const float4*)(sr + dc), s1 = *(const float4*)(sr + dc + 4);
    float cv[8] = {c0.x, c0.y, c0.z, c0.w, c1.x, c1.y, c1.z, c1.w};
    float sv[8] = {s0.x, s0.y, s0.z, s0.w, s1.x, s1.y, s1.z, s1.w};
    s16x8 o1, o2;
#pragma unroll
    for (int j = 0; j < 8; ++j) {
      float x1 = b2f((u16)a[j]), x2 = b2f((u16)bb[j]);
      o1[j] = (short)f2b((x1 * cv[j] - x2 * sv[j]) * m);
      o2[j] = (short)f2b((x2 * cv[j] + x1 * sv[j]) * m);
    }
    *(s16x8*)&row[ci] = o1;
    *(s16x8*)&row[ci + 64] = o2;
  } else {
    const int vb = bid - 5120;
    const int s0 = (vb & 31) * 64;
    const int d0 = ((vb >> 5) & 1) * 64;
    const int bk = vb >> 6;
    const int b = bk >> 3, kvh = bk & 7;
    const int slot = t & 7, r0 = t >> 3;
#pragma unroll
    for (int i = 0; i < 2; ++i) {
      int s_ = r0 + 32 * i;
      *(s16x8*)&tile[s_][slot * 8] =
          *(const s16x8*)(qkv + (size_t)(b * 2048 + s0 + s_) * 6144 + 5120 + kvh * 128 + d0 + slot * 8);
    }
    __syncthreads();
#pragma unroll
    for (int i = 0; i < 2; ++i) {
      int d_ = r0 + 32 * i;
      s16x8 v;
#pragma unroll
      for (int j = 0; j < 8; ++j) v[j] = (short)tile[slot * 8 + j][d_];
      *(s16x8*)(v_t + ((size_t)bk * 128 + d0 + d_) * 2048 + s0 + slot * 8) = v;
    }
  }
}

// Flash causal attention (round-15 champion).
__global__ void __launch_bounds__(256, 2) attn_kernel(const u16* __restrict__ qkv,
                                                      const u16* __restrict__ v_t,
                                                      u16* __restrict__ attn) {
  __shared__ __attribute__((aligned(16))) u16 Ks[64][136];
  __shared__ __attribute__((aligned(16))) u16 Vs[128][72];
  __shared__ __attribute__((aligned(16))) u16 Ps[4][32][72];
  const int t = threadIdx.x;
  const int f = blockIdx.x;
  const int xcd = f & 7, ix = f >> 3;
  const int g = (xcd << 1) | (ix >> 6);
  const int r_ = ix & 63;
  const int b = g >> 3, kvh = g & 7;
  const int qt = 15 - (r_ >> 2);
  const int h = kvh * 4 + (r_ & 3);
  const int q0 = qt * 128;
  const int w = t >> 6, lane = t & 63, lc = lane & 15, lg = lane >> 4;
  const int qw = q0 + w * 32;

  const u16* qbase = qkv + (size_t)(b * 2048) * 6144 + h * 128;
  const u16* kbase = qkv + (size_t)(b * 2048) * 6144 + 4096 + kvh * 128;
  const u16* vbase = v_t + (size_t)(b * 8 + kvh) * 128 * 2048;

  s16x8 qf[2][4];
#pragma unroll
  for (int mf = 0; mf < 2; ++mf)
#pragma unroll
    for (int ks = 0; ks < 4; ++ks)
      qf[mf][ks] = *(const s16x8*)(qbase + (size_t)(qw + mf * 16 + lc) * 6144 + ks * 32 + lg * 8);

  const f32x4 FZ = {0.f, 0.f, 0.f, 0.f};
  const short ONE = (short)0x3F80;
  const s16x8 ONES = {ONE, ONE, ONE, ONE, ONE, ONE, ONE, ONE};
  f32x4 o_acc[2][8];
  f32x4 l9[2];
  float m_run[2][4];
#pragma unroll
  for (int mf = 0; mf < 2; ++mf) {
#pragma unroll
    for (int nf = 0; nf < 8; ++nf) o_acc[mf][nf] = FZ;
    l9[mf] = FZ;
#pragma unroll
    for (int r = 0; r < 4; ++r) m_run[mf][r] = -3e38f;
  }

  const int ntiles = q0 / 64 + 2;
  s16x8 kr[4], vr[4];
#pragma unroll
  for (int i = 0; i < 4; ++i) {
    int c = i * 256 + t;
    kr[i] = *(const s16x8*)(kbase + (size_t)(c >> 4) * 6144 + (c & 15) * 8);
    vr[i] = *(const s16x8*)(vbase + (size_t)(c >> 3) * 2048 + (c & 7) * 8);
  }

  for (int kt = 0; kt < ntiles; ++kt) {
    const int k0 = kt * 64;
    __syncthreads();
#pragma unroll
    for (int i = 0; i < 4; ++i) {
      int c = i * 256 + t;
      *(s16x8*)&Ks[c >> 4][(c & 15) * 8] = kr[i];
      *(s16x8*)&Vs[c >> 3][(c & 7) * 8] = vr[i];
    }
    __syncthreads();
    if (kt + 1 < ntiles) {
      int k1 = k0 + 64;
#pragma unroll
      for (int i = 0; i < 4; ++i) {
        int c = i * 256 + t;
        kr[i] = *(const s16x8*)(kbase + (size_t)(k1 + (c >> 4)) * 6144 + (c & 15) * 8);
        vr[i] = *(const s16x8*)(vbase + (size_t)(c >> 3) * 2048 + k1 + (c & 7) * 8);
      }
    }
    if (k0 > qw + 31) continue;

    f32x4 sacc[2][4];
#pragma unroll
    for (int mf = 0; mf < 2; ++mf)
#pragma unroll
      for (int nf = 0; nf < 4; ++nf) sacc[mf][nf] = FZ;
#pragma unroll
    for (int ks = 0; ks < 4; ++ks) {
      s16x8 kf[4];
#pragma unroll
      for (int nf = 0; nf < 4; ++nf)
        kf[nf] = *(const s16x8*)&Ks[nf * 16 + lc][ks * 32 + lg * 8];
#pragma unroll
      for (int mf = 0; mf < 2; ++mf)
#pragma unroll
        for (int nf = 0; nf < 4; ++nf)
          sacc[mf][nf] = __builtin_amdgcn_mfma_f32_16x16x32_bf16(qf[mf][ks], kf[nf], sacc[mf][nf], 0, 0, 0);
    }

#pragma unroll
    for (int mf = 0; mf < 2; ++mf) {
      float pm[4] = {-3e38f, -3e38f, -3e38f, -3e38f};
      const bool dm = (k0 + 63 > qw + mf * 16);
      if (dm) {
#pragma unroll
        for (int nf = 0; nf < 4; ++nf) {
          int kv = k0 + nf * 16 + lc;
#pragma unroll
          for (int r = 0; r < 4; ++r) {
            int qg = qw + mf * 16 + lg * 4 + r;
            float sv = (kv <= qg) ? sacc[mf][nf][r] : -3e38f;
            sacc[mf][nf][r] = sv;
            pm[r] = fmaxf(pm[r], sv);
          }
        }
      } else {
#pragma unroll
        for (int nf = 0; nf < 4; ++nf)
#pragma unroll
          for (int r = 0; r < 4; ++r) pm[r] = fmaxf(pm[r], sacc[mf][nf][r]);
      }
#pragma unroll
      for (int r = 0; r < 4; ++r) {
        pm[r] = fmaxf(pm[r], __shfl_xor(pm[r], 1));
        pm[r] = fmaxf(pm[r], __shfl_xor(pm[r], 2));
        pm[r] = fmaxf(pm[r], __shfl_xor(pm[r], 4));
        pm[r] = fmaxf(pm[r], __shfl_xor(pm[r], 8));
      }
      bool need = false;
#pragma unroll
      for (int r = 0; r < 4; ++r) need |= (pm[r] > m_run[mf][r] + 8.0f);
      if (__any(need)) {
#pragma unroll
        for (int r = 0; r < 4; ++r) {
          float mnew = fmaxf(m_run[mf][r], pm[r]);
          float fsc = exp2f(m_run[mf][r] - mnew);
          m_run[mf][r] = mnew;
          l9[mf][r] *= fsc;
#pragma unroll
          for (int nf = 0; nf < 8; ++nf) o_acc[mf][nf][r] *= fsc;
        }
      }
#pragma unroll
      for (int nf = 0; nf < 4; ++nf)
#pragma unroll
        for (int r = 0; r < 4; ++r) {
          float p = exp2f(sacc[mf][nf][r] - m_run[mf][r]);
          Ps[w][mf * 16 + lg * 4 + r][nf * 16 + lc] = f2b(p);
        }
    }
#pragma unroll
    for (int ks = 0; ks < 2; ++ks) {
      s16x8 pf[2];
#pragma unroll
      for (int mf = 0; mf < 2; ++mf)
        pf[mf] = *(const s16x8*)&Ps[w][mf * 16 + lc][ks * 32 + lg * 8];
#pragma unroll
      for (int mf = 0; mf < 2; ++mf)
        l9[mf] = __builtin_amdgcn_mfma_f32_16x16x32_bf16(pf[mf], ONES, l9[mf], 0, 0, 0);
#pragma unroll
      for (int nf = 0; nf < 8; ++nf) {
        s16x8 vf = *(const s16x8*)&Vs[nf * 16 + lc][ks * 32 + lg * 8];
#pragma unroll
        for (int mf = 0; mf < 2; ++mf)
          o_acc[mf][nf] = __builtin_amdgcn_mfma_f32_16x16x32_bf16(pf[mf], vf, o_acc[mf][nf], 0, 0, 0);
      }
    }
  }

#pragma unroll
  for (int mf = 0; mf < 2; ++mf)
#pragma unroll
    for (int r = 0; r < 4; ++r) {
      float inv = 1.0f / l9[mf][r];
      int qg = qw + mf * 16 + lg * 4 + r;
#pragma unroll
      for (int nf = 0; nf < 8; ++nf)
        attn[(size_t)(b * 2048 + qg) * 4096 + h * 128 + nf * 16 + lc] =
            f2b(o_acc[mf][nf][r] * inv);
    }
}

extern "C" void kernel_launch(void* const* d_in, const int* in_sizes, int n_in,
                              void* d_out, int out_size, void* d_ws, size_t ws_size,
                              hipStream_t stream) {
  (void)in_sizes; (void)n_in; (void)out_size; (void)ws_size;
  const float* x = (const float*)d_in[0];
  const float* cosb = (const float*)d_in[1];
  const float* sinb = (const float*)d_in[2];
  const float* Wqkv = (const float*)d_in[3];
  const float* Wout = (const float*)d_in[4];
  float* out = (float*)d_out;
  char* ws = (char*)d_ws;

  u16* buf0 = (u16*)ws;
  u16* buf1 = (u16*)(ws + 50331648);
  u16* regc = (u16*)(ws + 100663296);

  prep_kernel<<<14336, 256, 0, stream>>>(x, Wqkv, regc, buf0);                  // xb + Wqkv_t
  gemm128_g1<<<768, 512, 0, stream>>>(regc, buf0, buf1, 4096, 6144, 4096);      // qkv (col-band XCD map)
  rv_kernel<<<6144, 256, 0, stream>>>(buf1, cosb, sinb, regc);                  // rope + v_t (merged)
  attn_kernel<<<1024, 256, 0, stream>>>(buf1, regc, buf0);                      // attn_out
  trans_bf16<<<dim3(64, 64), 256, 0, stream>>>(Wout, regc, 4096, 4096);         // Wout_t
  gemm256_g2<<<256, 512, 0, stream>>>(buf0, regc, out, 4096, 4096, 4096);       // out (quadrant XCD map)
}